// Round 1
// baseline (597.517 us; speedup 1.0000x reference)
//
#include <hip/hip_runtime.h>
#include <hip/hip_bf16.h>
#include <cmath>

// ---- problem constants ----
constexpr int cB  = 2;
constexpr int cS  = 1024;
constexpr int cNH = 32;
constexpr int cHD = 128;
constexpr int cHID = 4096;
constexpr int cM  = cB * cS;        // 2048 rows

typedef unsigned short u16;
typedef __bf16 bf16x8 __attribute__((ext_vector_type(8)));
typedef float  f32x4  __attribute__((ext_vector_type(4)));

__device__ __forceinline__ u16 f2b(float f) { return __builtin_bit_cast(u16, (__bf16)f); }

// ---------------- f32 -> bf16, 8 elems/thread ----------------
__global__ void cvt_bf16(const float* __restrict__ in, u16* __restrict__ out, int n8) {
  int i = blockIdx.x * blockDim.x + threadIdx.x;
  if (i >= n8) return;
  const float4* in4 = (const float4*)in;
  float4 a = in4[2 * i], b = in4[2 * i + 1];
  union { u16 u[8]; uint4 v; } r;
  r.u[0] = f2b(a.x); r.u[1] = f2b(a.y); r.u[2] = f2b(a.z); r.u[3] = f2b(a.w);
  r.u[4] = f2b(b.x); r.u[5] = f2b(b.y); r.u[6] = f2b(b.z); r.u[7] = f2b(b.w);
  ((uint4*)out)[i] = r.v;
}

// ---------------- RoPE cos/sin table: [B*S][64] ----------------
__global__ void rope_table_k(const int* __restrict__ pos,
                             float* __restrict__ cosT, float* __restrict__ sinT) {
  int idx = blockIdx.x * blockDim.x + threadIdx.x;   // < B*S*64
  int i = idx & 63, bs = idx >> 6;
  float p = (float)pos[bs];
  // inv_freq = 10000^(-i/64) = exp2(-i * log2(10000)/64)
  float freq = exp2f(-(float)i * (13.287712379549449f / 64.0f));
  float a = p * freq;
  float s, c;
  sincosf(a, &s, &c);
  cosT[idx] = c; sinT[idx] = s;
}

// ---------------- RoPE in-place on Q and K (bf16), interleaved pairs ------
__global__ void rope_apply(u16* __restrict__ Q, u16* __restrict__ Kb,
                           const float* __restrict__ cosT, const float* __restrict__ sinT) {
  int idx = blockIdx.x * blockDim.x + threadIdx.x;
  const int nPer = cB * cS * cNH * (cHD / 8);        // 1,048,576
  u16* P = (idx < nPer) ? Q : Kb;
  int t = (idx < nPer) ? idx : idx - nPer;
  int d8 = t & 15;                // which 8-elem chunk of head dim
  int h  = (t >> 4) & 31;
  int bs = t >> 9;                // b*S+s
  size_t base = ((size_t)bs * cNH + h) * cHD + d8 * 8;
  uint4 v = *reinterpret_cast<uint4*>(P + base);
  u16* u = reinterpret_cast<u16*>(&v);
  int pb = bs * 64 + d8 * 4;      // pair index base
  float4 cs = *reinterpret_cast<const float4*>(cosT + pb);
  float4 sn = *reinterpret_cast<const float4*>(sinT + pb);
  float co[4] = {cs.x, cs.y, cs.z, cs.w};
  float si[4] = {sn.x, sn.y, sn.z, sn.w};
#pragma unroll
  for (int p = 0; p < 4; ++p) {
    float e = (float)__builtin_bit_cast(__bf16, u[2 * p]);
    float o = (float)__builtin_bit_cast(__bf16, u[2 * p + 1]);
    float e2 = e * co[p] - o * si[p];
    float o2 = o * co[p] + e * si[p];
    u[2 * p]     = f2b(e2);
    u[2 * p + 1] = f2b(o2);
  }
  *reinterpret_cast<uint4*>(P + base) = v;
}

// ---------------- V [B,S,NH,HD] -> Vt [B*NH, HD, S] ----------------
__global__ void transpose_v(const u16* __restrict__ V, u16* __restrict__ Vt) {
  __shared__ u16 tile[32][33];
  int bh = blockIdx.z;                // b*NH + h
  int b = bh >> 5, h = bh & 31;
  int s0 = blockIdx.x * 32, d0 = blockIdx.y * 32;
  int tx = threadIdx.x & 31, ty0 = threadIdx.x >> 5;   // 8 rows per pass
#pragma unroll
  for (int i = 0; i < 4; ++i) {
    int r = ty0 + i * 8;
    tile[r][tx] = V[((size_t)(b * cS + s0 + r) * cNH + h) * cHD + d0 + tx];
  }
  __syncthreads();
#pragma unroll
  for (int i = 0; i < 4; ++i) {
    int r = ty0 + i * 8;  // d-local
    Vt[((size_t)bh * cHD + d0 + r) * cS + s0 + tx] = tile[tx][r];
  }
}

// ---------------- GEMM: C[M,N] = A[M,K] @ Bw[N,K]^T + bias ----------------
// 128x128 tile, 4 waves (each 64x64), BK=64, 16x16x32 bf16 MFMA.
// LDS rows are 128B; XOR chunk-swizzle (chunk ^= row&7) kills bank conflicts.
template <int OUT_BF16>
__global__ __launch_bounds__(256)
void gemm_bt(const u16* __restrict__ A, const u16* __restrict__ Bw,
             const float* __restrict__ bias, void* __restrict__ Cout,
             int N, int K) {
  __shared__ __align__(16) char sA[16384];
  __shared__ __align__(16) char sB[16384];
  const int tid = threadIdx.x;
  const int w = tid >> 6, lane = tid & 63;
  const int c = lane & 15, g = lane >> 4;
  const int m0 = blockIdx.y * 128, n0 = blockIdx.x * 128;
  const int wm = w >> 1, wn = w & 1;

  f32x4 acc[4][4] = {};

  const int nkt = K >> 6;
  for (int kt = 0; kt < nkt; ++kt) {
    uint4 va[4], vb[4];
#pragma unroll
    for (int i = 0; i < 4; ++i) {
      int cidx = (w * 4 + i) * 64 + lane;     // 0..1023 chunk id
      int row = cidx >> 3, lc = cidx & 7;     // 8 chunks (128B) per row
      va[i] = *(const uint4*)(A  + (size_t)(m0 + row) * K + kt * 64 + lc * 8);
      vb[i] = *(const uint4*)(Bw + (size_t)(n0 + row) * K + kt * 64 + lc * 8);
    }
#pragma unroll
    for (int i = 0; i < 4; ++i) {
      int cidx = (w * 4 + i) * 64 + lane;
      int row = cidx >> 3, lc = cidx & 7;
      int pc = lc ^ (row & 7);
      *(uint4*)(sA + row * 128 + pc * 16) = va[i];
      *(uint4*)(sB + row * 128 + pc * 16) = vb[i];
    }
    __syncthreads();

    bf16x8 af[2][4], bfr[2][4];
#pragma unroll
    for (int kf = 0; kf < 2; ++kf) {
#pragma unroll
      for (int f = 0; f < 4; ++f) {
        int ra = wm * 64 + f * 16 + c;
        af[kf][f] = *reinterpret_cast<const bf16x8*>(sA + ra * 128 + (((kf * 4 + g) ^ (ra & 7)) * 16));
        int rb = wn * 64 + f * 16 + c;
        bfr[kf][f] = *reinterpret_cast<const bf16x8*>(sB + rb * 128 + (((kf * 4 + g) ^ (rb & 7)) * 16));
      }
    }
#pragma unroll
    for (int kf = 0; kf < 2; ++kf)
#pragma unroll
      for (int mf = 0; mf < 4; ++mf)
#pragma unroll
        for (int nf = 0; nf < 4; ++nf)
          acc[mf][nf] = __builtin_amdgcn_mfma_f32_16x16x32_bf16(af[kf][mf], bfr[kf][nf], acc[mf][nf], 0, 0, 0);
    __syncthreads();
  }

  // epilogue: C row = m0+wm*64+mf*16+g*4+r ; col = n0+wn*64+nf*16+c
#pragma unroll
  for (int nf = 0; nf < 4; ++nf) {
    int col = n0 + wn * 64 + nf * 16 + c;
    float bv = bias[col];
#pragma unroll
    for (int mf = 0; mf < 4; ++mf) {
      int row = m0 + wm * 64 + mf * 16 + g * 4;
#pragma unroll
      for (int r = 0; r < 4; ++r) {
        float v = acc[mf][nf][r] + bv;
        if (OUT_BF16)
          ((u16*)Cout)[(size_t)(row + r) * N + col] = f2b(v);
        else
          ((float*)Cout)[(size_t)(row + r) * N + col] = v;
      }
    }
  }
}

// ---------------- flash attention (causal), 64 q-rows/block, 4 waves ------
// Q,K layout [B,S,NH,HD] bf16 ; Vt layout [B*NH,HD,S] bf16 ; O -> [B,S,NH,HD]
__global__ __launch_bounds__(256)
void attn_kernel(const u16* __restrict__ Q, const u16* __restrict__ Kb,
                 const u16* __restrict__ Vt, u16* __restrict__ O) {
  __shared__ __align__(16) char sK[16384];  // [64 k][128 d] swizzled, also reused for output
  __shared__ __align__(16) char sV[16384];  // [128 d][64 k] swizzled
  __shared__ __align__(16) char sP[8192];   // per-wave [16 q][64 k] swizzled
  const int tid = threadIdx.x, w = tid >> 6, lane = tid & 63;
  const int c = lane & 15, g = lane >> 4;
  const int qt = blockIdx.x, bh = blockIdx.y;
  const int b = bh >> 5, h = bh & 31;
  const int q0 = qt * 64;
  const float kSc = 0.12751744f;  // log2(e)/sqrt(128)

  // Q fragments (A operand): row = q0 + w*16 + c, d = df*32 + g*8 + j
  bf16x8 qf[4];
  {
    size_t qrow = ((size_t)(b * cS + q0 + w * 16 + c) * cNH + h) * cHD;
#pragma unroll
    for (int df = 0; df < 4; ++df)
      qf[df] = *reinterpret_cast<const bf16x8*>(Q + qrow + df * 32 + g * 8);
  }

  f32x4 o[8] = {};
  float m[4]  = {-1e30f, -1e30f, -1e30f, -1e30f};
  float ls[4] = {0.f, 0.f, 0.f, 0.f};

  for (int t = 0; t <= qt; ++t) {
    // ---- stage K tile [64][128] and Vt tile [128][64] (reg->LDS, swizzled)
#pragma unroll
    for (int i = 0; i < 4; ++i) {
      int cidx = i * 256 + tid;
      {
        int row = cidx >> 4, ch = cidx & 15;   // 16 chunks/row (256B)
        uint4 v = *reinterpret_cast<const uint4*>(
            Kb + ((size_t)(b * cS + t * 64 + row) * cNH + h) * cHD + ch * 8);
        *reinterpret_cast<uint4*>(sK + row * 256 + ((ch ^ (row & 7)) * 16)) = v;
      }
      {
        int row = cidx >> 3, ch = cidx & 7;    // 8 chunks/row (128B)
        uint4 v = *reinterpret_cast<const uint4*>(
            Vt + ((size_t)bh * cHD + row) * cS + t * 64 + ch * 8);
        *reinterpret_cast<uint4*>(sV + row * 128 + ((ch ^ (row & 7)) * 16)) = v;
      }
    }
    __syncthreads();

    // ---- QK^T: scores [16 q][64 k] in 4 col-frags
    f32x4 sc[4] = {};
#pragma unroll
    for (int df = 0; df < 4; ++df) {
      bf16x8 kb[4];
#pragma unroll
      for (int cf = 0; cf < 4; ++cf) {
        int kr = cf * 16 + c;
        kb[cf] = *reinterpret_cast<const bf16x8*>(sK + kr * 256 + (((df * 4 + g) ^ (kr & 7)) * 16));
      }
#pragma unroll
      for (int cf = 0; cf < 4; ++cf)
        sc[cf] = __builtin_amdgcn_mfma_f32_16x16x32_bf16(qf[df], kb[cf], sc[cf], 0, 0, 0);
    }

    // ---- causal mask on diagonal tile
    if (t == qt) {
#pragma unroll
      for (int cf = 0; cf < 4; ++cf) {
        int kg = t * 64 + cf * 16 + c;
#pragma unroll
        for (int r = 0; r < 4; ++r) {
          int qg = q0 + w * 16 + g * 4 + r;
          if (kg > qg) sc[cf][r] = -1e30f;
        }
      }
    }

    // ---- online softmax (wave-parallel: reduce over 16-lane column groups)
    float alpha[4];
#pragma unroll
    for (int r = 0; r < 4; ++r) {
      float v = fmaxf(fmaxf(sc[0][r], sc[1][r]), fmaxf(sc[2][r], sc[3][r]));
      v = fmaxf(v, __shfl_xor(v, 1));
      v = fmaxf(v, __shfl_xor(v, 2));
      v = fmaxf(v, __shfl_xor(v, 4));
      v = fmaxf(v, __shfl_xor(v, 8));
      float mn = fmaxf(m[r], v);
      alpha[r] = exp2f((m[r] - mn) * kSc);
      m[r] = mn;
    }
    float rs[4] = {0.f, 0.f, 0.f, 0.f};
#pragma unroll
    for (int cf = 0; cf < 4; ++cf)
#pragma unroll
      for (int r = 0; r < 4; ++r) {
        float p = exp2f((sc[cf][r] - m[r]) * kSc);
        sc[cf][r] = p;
        rs[r] += p;
      }
#pragma unroll
    for (int r = 0; r < 4; ++r) {
      float v = rs[r];
      v += __shfl_xor(v, 1); v += __shfl_xor(v, 2);
      v += __shfl_xor(v, 4); v += __shfl_xor(v, 8);
      ls[r] = ls[r] * alpha[r] + v;
    }
#pragma unroll
    for (int nf = 0; nf < 8; ++nf)
#pragma unroll
      for (int r = 0; r < 4; ++r)
        o[nf][r] *= alpha[r];

    // ---- P (C layout) -> per-wave LDS (bf16, swizzled) for A-operand reload
    char* myP = sP + w * 2048;
#pragma unroll
    for (int cf = 0; cf < 4; ++cf) {
      int kcol = cf * 16 + c;
      int chunk = kcol >> 3, within = kcol & 7;
#pragma unroll
      for (int r = 0; r < 4; ++r) {
        int qr = g * 4 + r;
        *reinterpret_cast<u16*>(myP + qr * 128 + ((chunk ^ (qr & 7)) * 16) + within * 2) =
            f2b(sc[cf][r]);
      }
    }
    bf16x8 pa[2];
#pragma unroll
    for (int kf = 0; kf < 2; ++kf)
      pa[kf] = *reinterpret_cast<const bf16x8*>(myP + c * 128 + (((kf * 4 + g) ^ (c & 7)) * 16));

    // ---- PV: O[16 q][128 d] += P[16][64] x V[64][128]
#pragma unroll
    for (int kf = 0; kf < 2; ++kf) {
#pragma unroll
      for (int nf = 0; nf < 8; ++nf) {
        int dr = nf * 16 + c;
        bf16x8 vb = *reinterpret_cast<const bf16x8*>(sV + dr * 128 + (((kf * 4 + g) ^ (dr & 7)) * 16));
        o[nf] = __builtin_amdgcn_mfma_f32_16x16x32_bf16(pa[kf], vb, o[nf], 0, 0, 0);
      }
    }
    __syncthreads();
  }

  // ---- finalize: O /= l, round-trip through sK for coalesced global store
#pragma unroll
  for (int nf = 0; nf < 8; ++nf) {
#pragma unroll
    for (int r = 0; r < 4; ++r) {
      float v = o[nf][r] / ls[r];
      int qr = w * 16 + g * 4 + r;
      *reinterpret_cast<u16*>(sK + qr * 256 + (nf * 16 + c) * 2) = f2b(v);
    }
  }
  __syncthreads();
#pragma unroll
  for (int i = 0; i < 4; ++i) {
    int cidx = i * 256 + tid;
    int row = cidx >> 4, ch = cidx & 15;
    uint4 v = *reinterpret_cast<const uint4*>(sK + row * 256 + ch * 16);
    *reinterpret_cast<uint4*>(O + ((size_t)(b * cS + q0 + row) * cNH + h) * cHD + ch * 8) = v;
  }
}

// ---------------- host ----------------
extern "C" void kernel_launch(void* const* d_in, const int* in_sizes, int n_in,
                              void* d_out, int out_size, void* d_ws, size_t ws_size,
                              hipStream_t stream) {
  const float* x  = (const float*)d_in[0];
  const float* Wq = (const float*)d_in[1];
  const float* bq = (const float*)d_in[2];
  const float* Wk = (const float*)d_in[3];
  const float* bk = (const float*)d_in[4];
  const float* Wv = (const float*)d_in[5];
  const float* bv = (const float*)d_in[6];
  const float* Wo = (const float*)d_in[7];
  const float* bo = (const float*)d_in[8];
  const int*  pos = (const int*)d_in[9];
  float* out = (float*)d_out;

  char* ws = (char*)d_ws;
  const size_t MB = 1u << 20;
  u16* xb = (u16*)(ws);                 // 16 MB (x bf16), later reused as Vt
  u16* Wb = (u16*)(ws + 16 * MB);       // 32 MB (current weight bf16)
  u16* Qb = (u16*)(ws + 48 * MB);       // 16 MB
  u16* Kb = (u16*)(ws + 64 * MB);       // 16 MB
  u16* Vb = (u16*)(ws + 80 * MB);       // 16 MB, later reused as attention out
  u16* Vt = xb;                         // alias: x no longer needed after V GEMM
  u16* Ab = Vb;                         // alias: V raw no longer needed after transpose
  float* cosT = (float*)(ws + 96 * MB); // 0.5 MB
  float* sinT = cosT + cB * cS * 64;    // 0.5 MB
  // total ws use: 97 MB

  const int W8 = (cHID * cHID) / 8;     // 2,097,152
  const int X8 = (cM * cHID) / 8;       // 1,048,576

  cvt_bf16<<<X8 / 256, 256, 0, stream>>>(x, xb, X8);
  cvt_bf16<<<W8 / 256, 256, 0, stream>>>(Wq, Wb, W8);
  gemm_bt<1><<<dim3(32, 16), 256, 0, stream>>>(xb, Wb, bq, Qb, cHID, cHID);
  cvt_bf16<<<W8 / 256, 256, 0, stream>>>(Wk, Wb, W8);
  gemm_bt<1><<<dim3(32, 16), 256, 0, stream>>>(xb, Wb, bk, Kb, cHID, cHID);
  cvt_bf16<<<W8 / 256, 256, 0, stream>>>(Wv, Wb, W8);
  gemm_bt<1><<<dim3(32, 16), 256, 0, stream>>>(xb, Wb, bv, Vb, cHID, cHID);

  rope_table_k<<<(cB * cS * 64) / 256, 256, 0, stream>>>(pos, cosT, sinT);
  rope_apply<<<(2 * cB * cS * cNH * (cHD / 8)) / 256, 256, 0, stream>>>(Qb, Kb, cosT, sinT);

  transpose_v<<<dim3(cS / 32, cHD / 32, cB * cNH), 256, 0, stream>>>(Vb, Vt);
  attn_kernel<<<dim3(cS / 64, cB * cNH), 256, 0, stream>>>(Qb, Kb, Vt, Ab);

  cvt_bf16<<<W8 / 256, 256, 0, stream>>>(Wo, Wb, W8);
  gemm_bt<0><<<dim3(32, 16), 256, 0, stream>>>(Ab, Wb, bo, out, cHID, cHID);
}

// Round 2
// 579.103 us; speedup vs baseline: 1.0318x; 1.0318x over previous
//
#include <hip/hip_runtime.h>
#include <hip/hip_bf16.h>
#include <cmath>

// ---- problem constants ----
constexpr int cB  = 2;
constexpr int cS  = 1024;
constexpr int cNH = 32;
constexpr int cHD = 128;
constexpr int cHID = 4096;
constexpr int cM  = cB * cS;        // 2048 rows

typedef unsigned short u16;
typedef __bf16 bf16x8 __attribute__((ext_vector_type(8)));
typedef float  f32x4  __attribute__((ext_vector_type(4)));

__device__ __forceinline__ u16 f2b(float f) { return __builtin_bit_cast(u16, (__bf16)f); }

// ---------------- f32 -> bf16, 8 elems/thread ----------------
__global__ void cvt_bf16(const float* __restrict__ in, u16* __restrict__ out, int n8) {
  int i = blockIdx.x * blockDim.x + threadIdx.x;
  if (i >= n8) return;
  const float4* in4 = (const float4*)in;
  float4 a = in4[2 * i], b = in4[2 * i + 1];
  union { u16 u[8]; uint4 v; } r;
  r.u[0] = f2b(a.x); r.u[1] = f2b(a.y); r.u[2] = f2b(a.z); r.u[3] = f2b(a.w);
  r.u[4] = f2b(b.x); r.u[5] = f2b(b.y); r.u[6] = f2b(b.z); r.u[7] = f2b(b.w);
  ((uint4*)out)[i] = r.v;
}

// ---------------- RoPE cos/sin table: [B*S][64] ----------------
__global__ void rope_table_k(const int* __restrict__ pos,
                             float* __restrict__ cosT, float* __restrict__ sinT) {
  int idx = blockIdx.x * blockDim.x + threadIdx.x;   // < B*S*64
  int i = idx & 63, bs = idx >> 6;
  float p = (float)pos[bs];
  float freq = exp2f(-(float)i * (13.287712379549449f / 64.0f));
  float a = p * freq;
  float s, c;
  sincosf(a, &s, &c);
  cosT[idx] = c; sinT[idx] = s;
}

// ---------------- RoPE in-place on Q and K (bf16), interleaved pairs ------
__global__ void rope_apply(u16* __restrict__ Q, u16* __restrict__ Kb,
                           const float* __restrict__ cosT, const float* __restrict__ sinT) {
  int idx = blockIdx.x * blockDim.x + threadIdx.x;
  const int nPer = cB * cS * cNH * (cHD / 8);        // 1,048,576
  u16* P = (idx < nPer) ? Q : Kb;
  int t = (idx < nPer) ? idx : idx - nPer;
  int d8 = t & 15;
  int h  = (t >> 4) & 31;
  int bs = t >> 9;
  size_t base = ((size_t)bs * cNH + h) * cHD + d8 * 8;
  uint4 v = *reinterpret_cast<uint4*>(P + base);
  u16* u = reinterpret_cast<u16*>(&v);
  int pb = bs * 64 + d8 * 4;
  float4 cs = *reinterpret_cast<const float4*>(cosT + pb);
  float4 sn = *reinterpret_cast<const float4*>(sinT + pb);
  float co[4] = {cs.x, cs.y, cs.z, cs.w};
  float si[4] = {sn.x, sn.y, sn.z, sn.w};
#pragma unroll
  for (int p = 0; p < 4; ++p) {
    float e = (float)__builtin_bit_cast(__bf16, u[2 * p]);
    float o = (float)__builtin_bit_cast(__bf16, u[2 * p + 1]);
    float e2 = e * co[p] - o * si[p];
    float o2 = o * co[p] + e * si[p];
    u[2 * p]     = f2b(e2);
    u[2 * p + 1] = f2b(o2);
  }
  *reinterpret_cast<uint4*>(P + base) = v;
}

// ---------------- V [B,S,NH,HD] -> Vt [B*NH, HD, S] ----------------
__global__ void transpose_v(const u16* __restrict__ V, u16* __restrict__ Vt) {
  __shared__ u16 tile[32][33];
  int bh = blockIdx.z;
  int b = bh >> 5, h = bh & 31;
  int s0 = blockIdx.x * 32, d0 = blockIdx.y * 32;
  int tx = threadIdx.x & 31, ty0 = threadIdx.x >> 5;
#pragma unroll
  for (int i = 0; i < 4; ++i) {
    int r = ty0 + i * 8;
    tile[r][tx] = V[((size_t)(b * cS + s0 + r) * cNH + h) * cHD + d0 + tx];
  }
  __syncthreads();
#pragma unroll
  for (int i = 0; i < 4; ++i) {
    int r = ty0 + i * 8;
    Vt[((size_t)bh * cHD + d0 + r) * cS + s0 + tx] = tile[tx][r];
  }
}

// ---------------- GEMM: C[M,N] = A[M,K] @ Bw[N,K]^T + bias ----------------
// m97 structure: 128x128 tile, 4 waves, BK=64, global_load_lds width-16 into
// LINEAR LDS [128][64] (T2 swizzle is measured-null at this structure).
template <int OUT_BF16>
__global__ __launch_bounds__(256)
void gemm_bt(const u16* __restrict__ A, const u16* __restrict__ Bw,
             const float* __restrict__ bias, void* __restrict__ Cout,
             int N, int K) {
  __shared__ __align__(16) u16 sA[128 * 64];
  __shared__ __align__(16) u16 sB[128 * 64];
  const int tid = threadIdx.x;
  const int w = tid >> 6, lane = tid & 63;
  const int c = lane & 15, g = lane >> 4;
  const int m0 = blockIdx.y * 128, n0 = blockIdx.x * 128;
  const int wm = w >> 1, wn = w & 1;

  f32x4 acc[4][4] = {};

  const int nkt = K >> 6;
  for (int kt = 0; kt < nkt; ++kt) {
    // stage A and B tiles direct to LDS: per call, wave-uniform LDS base
    // (j*4+w)*1024B, lane writes base+lane*16; global source per-lane.
#pragma unroll
    for (int j = 0; j < 4; ++j) {
      int chunk = (j * 4 + w) * 64 + lane;       // 0..1023
      int row = chunk >> 3, lc = chunk & 7;      // 8 chunks (128B) per row
      __builtin_amdgcn_global_load_lds(
          (const void*)(A + (size_t)(m0 + row) * K + kt * 64 + lc * 8),
          (void*)(sA + (size_t)(j * 4 + w) * 512), 16, 0, 0);
      __builtin_amdgcn_global_load_lds(
          (const void*)(Bw + (size_t)(n0 + row) * K + kt * 64 + lc * 8),
          (void*)(sB + (size_t)(j * 4 + w) * 512), 16, 0, 0);
    }
    __syncthreads();

    bf16x8 af[2][4], bfr[2][4];
#pragma unroll
    for (int kf = 0; kf < 2; ++kf) {
#pragma unroll
      for (int f = 0; f < 4; ++f) {
        int ra = wm * 64 + f * 16 + c;
        af[kf][f] = *reinterpret_cast<const bf16x8*>(sA + ra * 64 + (kf * 4 + g) * 8);
        int rb = wn * 64 + f * 16 + c;
        bfr[kf][f] = *reinterpret_cast<const bf16x8*>(sB + rb * 64 + (kf * 4 + g) * 8);
      }
    }
#pragma unroll
    for (int kf = 0; kf < 2; ++kf)
#pragma unroll
      for (int mf = 0; mf < 4; ++mf)
#pragma unroll
        for (int nf = 0; nf < 4; ++nf)
          acc[mf][nf] = __builtin_amdgcn_mfma_f32_16x16x32_bf16(af[kf][mf], bfr[kf][nf], acc[mf][nf], 0, 0, 0);
    __syncthreads();
  }

  // epilogue: C row = m0+wm*64+mf*16+g*4+r ; col = n0+wn*64+nf*16+c
#pragma unroll
  for (int nf = 0; nf < 4; ++nf) {
    int col = n0 + wn * 64 + nf * 16 + c;
    float bv = bias[col];
#pragma unroll
    for (int mf = 0; mf < 4; ++mf) {
      int row = m0 + wm * 64 + mf * 16 + g * 4;
#pragma unroll
      for (int r = 0; r < 4; ++r) {
        float v = acc[mf][nf][r] + bv;
        if (OUT_BF16)
          ((u16*)Cout)[(size_t)(row + r) * N + col] = f2b(v);
        else
          ((float*)Cout)[(size_t)(row + r) * N + col] = v;
      }
    }
  }
}

// ---------------- flash attention (causal), paired q-tiles, 4 waves -------
// Block x handles q-tiles qtA=x and qtB=15-x (17 tile-computations, uniform).
// K/V staged once for the shared prefix; double-buffered LDS, ONE barrier per
// tile; T14 split: issue loads(t+1) before compute(t), ds_write after.
__global__ __launch_bounds__(256, 2)
void attn_kernel(const u16* __restrict__ Q, const u16* __restrict__ Kb,
                 const u16* __restrict__ Vt, u16* __restrict__ O) {
  __shared__ __align__(16) char sK[2][16384];  // [64 k][128 d] swizzled
  __shared__ __align__(16) char sV[2][16384];  // [128 d][64 k] swizzled
  __shared__ __align__(16) char sP[8192];      // per-wave [16 q][64 k] swizzled
  const int tid = threadIdx.x, w = tid >> 6, lane = tid & 63;
  const int c = lane & 15, g = lane >> 4;
  const int bh = blockIdx.y;
  const int b = bh >> 5, h = bh & 31;
  const int NT = cS / 64;                       // 16
  const int qtA = blockIdx.x, qtB = NT - 1 - blockIdx.x;  // qtA in 0..7
  const float kSc = 0.12751744f;                // log2(e)/sqrt(128)

  // Q fragments for both q-tiles: row = q0 + w*16 + c, d = df*32 + g*8
  bf16x8 qf[2][4];
#pragma unroll
  for (int s = 0; s < 2; ++s) {
    int q0s = (s ? qtA : qtB) * 64;
    size_t qrow = ((size_t)(b * cS + q0s + w * 16 + c) * cNH + h) * cHD;
#pragma unroll
    for (int df = 0; df < 4; ++df)
      qf[s][df] = *reinterpret_cast<const bf16x8*>(Q + qrow + df * 32 + g * 8);
  }

  f32x4 o[2][8] = {};
  float mx[2][4], ls[2][4];
#pragma unroll
  for (int s = 0; s < 2; ++s)
#pragma unroll
    for (int r = 0; r < 4; ++r) { mx[s][r] = -1e30f; ls[s][r] = 0.f; }

  uint4 kv[4], vv[4];
#define LOADT(t)                                                               \
  {                                                                            \
    _Pragma("unroll") for (int i = 0; i < 4; ++i) {                            \
      int cidx = i * 256 + tid;                                                \
      { int row = cidx >> 4, ch = cidx & 15;                                   \
        kv[i] = *reinterpret_cast<const uint4*>(                               \
            Kb + ((size_t)(b * cS + (t) * 64 + row) * cNH + h) * cHD + ch * 8); } \
      { int row = cidx >> 3, ch = cidx & 7;                                    \
        vv[i] = *reinterpret_cast<const uint4*>(                               \
            Vt + ((size_t)bh * cHD + row) * cS + (t) * 64 + ch * 8); }         \
    }                                                                          \
  }
#define WRITET(buf)                                                            \
  {                                                                            \
    _Pragma("unroll") for (int i = 0; i < 4; ++i) {                            \
      int cidx = i * 256 + tid;                                                \
      { int row = cidx >> 4, ch = cidx & 15;                                   \
        *reinterpret_cast<uint4*>(sK[buf] + row * 256 + ((ch ^ (row & 7)) * 16)) = kv[i]; } \
      { int row = cidx >> 3, ch = cidx & 7;                                    \
        *reinterpret_cast<uint4*>(sV[buf] + row * 128 + ((ch ^ (row & 7)) * 16)) = vv[i]; } \
    }                                                                          \
  }

  LOADT(0);
  WRITET(0);
  int cur = 0;

  for (int t = 0; t <= qtB; ++t) {
    __syncthreads();                 // buf[cur] (tile t) visible to all waves
    if (t < qtB) LOADT(t + 1);       // issue-early: latency hides under compute

#pragma unroll
    for (int s = 0; s < 2; ++s) {
      const int qt_s = s ? qtA : qtB;
      if (t > qt_s) continue;        // only possible for s==1 (wave-uniform)
      const int q0_s = qt_s * 64;

      // ---- QK^T: scores [16 q][64 k] in 4 col-frags
      f32x4 sc[4] = {};
#pragma unroll
      for (int df = 0; df < 4; ++df) {
        bf16x8 kb[4];
#pragma unroll
        for (int cf = 0; cf < 4; ++cf) {
          int kr = cf * 16 + c;
          kb[cf] = *reinterpret_cast<const bf16x8*>(sK[cur] + kr * 256 + (((df * 4 + g) ^ (kr & 7)) * 16));
        }
#pragma unroll
        for (int cf = 0; cf < 4; ++cf)
          sc[cf] = __builtin_amdgcn_mfma_f32_16x16x32_bf16(qf[s][df], kb[cf], sc[cf], 0, 0, 0);
      }

      // ---- causal mask on diagonal tile
      if (t == qt_s) {
#pragma unroll
        for (int cf = 0; cf < 4; ++cf) {
          int kg = t * 64 + cf * 16 + c;
#pragma unroll
          for (int r = 0; r < 4; ++r) {
            int qg = q0_s + w * 16 + g * 4 + r;
            if (kg > qg) sc[cf][r] = -1e30f;
          }
        }
      }

      // ---- online softmax (wave-parallel over 16-lane column groups)
      float alpha[4];
#pragma unroll
      for (int r = 0; r < 4; ++r) {
        float v = fmaxf(fmaxf(sc[0][r], sc[1][r]), fmaxf(sc[2][r], sc[3][r]));
        v = fmaxf(v, __shfl_xor(v, 1));
        v = fmaxf(v, __shfl_xor(v, 2));
        v = fmaxf(v, __shfl_xor(v, 4));
        v = fmaxf(v, __shfl_xor(v, 8));
        float mn = fmaxf(mx[s][r], v);
        alpha[r] = exp2f((mx[s][r] - mn) * kSc);
        mx[s][r] = mn;
      }
      float rs[4] = {0.f, 0.f, 0.f, 0.f};
#pragma unroll
      for (int cf = 0; cf < 4; ++cf)
#pragma unroll
        for (int r = 0; r < 4; ++r) {
          float p = exp2f((sc[cf][r] - mx[s][r]) * kSc);
          sc[cf][r] = p;
          rs[r] += p;
        }
#pragma unroll
      for (int r = 0; r < 4; ++r) {
        float v = rs[r];
        v += __shfl_xor(v, 1); v += __shfl_xor(v, 2);
        v += __shfl_xor(v, 4); v += __shfl_xor(v, 8);
        ls[s][r] = ls[s][r] * alpha[r] + v;
      }
#pragma unroll
      for (int nf = 0; nf < 8; ++nf)
#pragma unroll
        for (int r = 0; r < 4; ++r)
          o[s][nf][r] *= alpha[r];

      // ---- P (C layout) -> per-wave LDS (bf16, swizzled) for A-operand
      char* myP = sP + w * 2048;
#pragma unroll
      for (int cf = 0; cf < 4; ++cf) {
        int kcol = cf * 16 + c;
        int chunk = kcol >> 3, within = kcol & 7;
#pragma unroll
        for (int r = 0; r < 4; ++r) {
          int qr = g * 4 + r;
          *reinterpret_cast<u16*>(myP + qr * 128 + ((chunk ^ (qr & 7)) * 16) + within * 2) =
              f2b(sc[cf][r]);
        }
      }
      bf16x8 pa[2];
#pragma unroll
      for (int kf = 0; kf < 2; ++kf)
        pa[kf] = *reinterpret_cast<const bf16x8*>(myP + c * 128 + (((kf * 4 + g) ^ (c & 7)) * 16));

      // ---- PV: O[16 q][128 d] += P[16][64] x V[64][128]
#pragma unroll
      for (int kf = 0; kf < 2; ++kf) {
#pragma unroll
        for (int nf = 0; nf < 8; ++nf) {
          int dr = nf * 16 + c;
          bf16x8 vb = *reinterpret_cast<const bf16x8*>(sV[cur] + dr * 128 + (((kf * 4 + g) ^ (dr & 7)) * 16));
          o[s][nf] = __builtin_amdgcn_mfma_f32_16x16x32_bf16(pa[kf], vb, o[s][nf], 0, 0, 0);
        }
      }
    }

    if (t < qtB) { WRITET(cur ^ 1); cur ^= 1; }  // write-late: buf[cur^1] held
                                                 // tile t-1, all readers done
  }

  // ---- finalize: O /= l; stage q-tile B output in sK[0], A in sK[1]
  __syncthreads();
#pragma unroll
  for (int s = 0; s < 2; ++s) {
#pragma unroll
    for (int nf = 0; nf < 8; ++nf) {
#pragma unroll
      for (int r = 0; r < 4; ++r) {
        float v = o[s][nf][r] / ls[s][r];
        int qr = w * 16 + g * 4 + r;
        *reinterpret_cast<u16*>(sK[s] + qr * 256 + (nf * 16 + c) * 2) = f2b(v);
      }
    }
  }
  __syncthreads();
#pragma unroll
  for (int s = 0; s < 2; ++s) {
    int q0_s = (s ? qtA : qtB) * 64;
#pragma unroll
    for (int i = 0; i < 4; ++i) {
      int cidx = i * 256 + tid;
      int row = cidx >> 4, ch = cidx & 15;
      uint4 v = *reinterpret_cast<const uint4*>(sK[s] + row * 256 + ch * 16);
      *reinterpret_cast<uint4*>(O + ((size_t)(b * cS + q0_s + row) * cNH + h) * cHD + ch * 8) = v;
    }
  }
#undef LOADT
#undef WRITET
}

// ---------------- host ----------------
extern "C" void kernel_launch(void* const* d_in, const int* in_sizes, int n_in,
                              void* d_out, int out_size, void* d_ws, size_t ws_size,
                              hipStream_t stream) {
  const float* x  = (const float*)d_in[0];
  const float* Wq = (const float*)d_in[1];
  const float* bq = (const float*)d_in[2];
  const float* Wk = (const float*)d_in[3];
  const float* bk = (const float*)d_in[4];
  const float* Wv = (const float*)d_in[5];
  const float* bv = (const float*)d_in[6];
  const float* Wo = (const float*)d_in[7];
  const float* bo = (const float*)d_in[8];
  const int*  pos = (const int*)d_in[9];
  float* out = (float*)d_out;

  char* ws = (char*)d_ws;
  const size_t MB = 1u << 20;
  u16* xb = (u16*)(ws);                 // 16 MB (x bf16), later reused as Vt
  u16* Wb = (u16*)(ws + 16 * MB);       // 32 MB (current weight bf16)
  u16* Qb = (u16*)(ws + 48 * MB);       // 16 MB
  u16* Kb = (u16*)(ws + 64 * MB);       // 16 MB
  u16* Vb = (u16*)(ws + 80 * MB);       // 16 MB, later reused as attention out
  u16* Vt = xb;                         // alias: x no longer needed after V GEMM
  u16* Ab = Vb;                         // alias: V raw no longer needed after transpose
  float* cosT = (float*)(ws + 96 * MB); // 0.5 MB
  float* sinT = cosT + cB * cS * 64;    // 0.5 MB

  const int W8 = (cHID * cHID) / 8;     // 2,097,152
  const int X8 = (cM * cHID) / 8;       // 1,048,576

  cvt_bf16<<<X8 / 256, 256, 0, stream>>>(x, xb, X8);
  cvt_bf16<<<W8 / 256, 256, 0, stream>>>(Wq, Wb, W8);
  gemm_bt<1><<<dim3(32, 16), 256, 0, stream>>>(xb, Wb, bq, Qb, cHID, cHID);
  cvt_bf16<<<W8 / 256, 256, 0, stream>>>(Wk, Wb, W8);
  gemm_bt<1><<<dim3(32, 16), 256, 0, stream>>>(xb, Wb, bk, Kb, cHID, cHID);
  cvt_bf16<<<W8 / 256, 256, 0, stream>>>(Wv, Wb, W8);
  gemm_bt<1><<<dim3(32, 16), 256, 0, stream>>>(xb, Wb, bv, Vb, cHID, cHID);

  rope_table_k<<<(cB * cS * 64) / 256, 256, 0, stream>>>(pos, cosT, sinT);
  rope_apply<<<(2 * cB * cS * cNH * (cHD / 8)) / 256, 256, 0, stream>>>(Qb, Kb, cosT, sinT);

  transpose_v<<<dim3(cS / 32, cHD / 32, cB * cNH), 256, 0, stream>>>(Vb, Vt);
  attn_kernel<<<dim3(cS / 128, cB * cNH), 256, 0, stream>>>(Qb, Kb, Vt, Ab);

  cvt_bf16<<<W8 / 256, 256, 0, stream>>>(Wo, Wb, W8);
  gemm_bt<0><<<dim3(32, 16), 256, 0, stream>>>(Ab, Wb, bo, out, cHID, cHID);
}